// Round 6
// baseline (245.740 us; speedup 1.0000x reference)
//
#include <hip/hip_runtime.h>

typedef unsigned short u16;
typedef __bf16 bf16x8 __attribute__((ext_vector_type(8)));
typedef float f32x4 __attribute__((ext_vector_type(4)));
typedef unsigned short u16x8 __attribute__((ext_vector_type(8)));

#define F_FACES 65536
#define N_FACES 131072
// ws layout (bytes):
//   [0,256)        zeropage (zeros; masked-gather target)
//   [256,3328)     W2 folded fp32  [b][o][i]  (768 floats)
//   [4352,594176)  W1 folded bf16  [b][k][o][i] (2*9*128*128)
//   [594176, +16777216*2) const bf16 copy [F][C]
#define WS_W2F 256
#define WS_W1 4352
#define WS_CONST 594176
#define XELEMS 16777216  // N_FACES*128
#define G512 0.04419417382415922f   // 1/sqrt(512)
#define G128 0.08838834764831845f   // 1/sqrt(128)

__device__ inline u16 f2bf(float f) {
    unsigned u = __builtin_bit_cast(unsigned, f);
    unsigned r = (u + 0x7fffu + ((u >> 16) & 1u)) >> 16;
    return (u16)r;
}

__device__ inline void gl_lds16(const void* g, void* l) {
    __builtin_amdgcn_global_load_lds(
        (const __attribute__((address_space(1))) void*)g,
        (__attribute__((address_space(3))) void*)l, 16, 0, 0);
}

__device__ inline float dot512(const float* a, const float* b) {
    float s = 0.f;
    for (int j = 0; j < 512; j += 4) {
        float4 x = *(const float4*)(a + j);
        float4 y = *(const float4*)(b + j);
        s += x.x * y.x + x.y * y.y + x.z * y.z + x.w * y.w;
    }
    return s;
}

// ---------------- kernel 0: ALL preprocessing in one launch ----------------
// blocks [0,4096): const fp32->bf16 cvt
// blocks [4096,4352): demod+fold W1 for (b,o) = blockIdx-4096 (recomputes styles1 locally)
// block  4352: zeropage + styles2 + W2 fold
__global__ __launch_bounds__(256) void k0_all(
    const float* __restrict__ cst, const float* __restrict__ wsv,
    const float* __restrict__ a1W, const float* __restrict__ a1b,
    const float* __restrict__ a2W, const float* __restrict__ a2b,
    const float* __restrict__ w1g, const float* __restrict__ w2,
    unsigned char* __restrict__ wsb)
{
    __shared__ float sh[392];  // p[256] | s1ld[128] | wred[4]  (fold role)
    int bid = blockIdx.x, tid = threadIdx.x;
    unsigned char* wsb_nr = wsb;  // non-restrict alias for mixed rw

    if (bid < 4096) {
        // ---- cvt role ----
        int base = (bid * 256 + tid) * 8;
        const float* src = cst + base;
        u16* dst = (u16*)(wsb_nr + WS_CONST) + base;
        float4 a = *(const float4*)(src);
        float4 c = *(const float4*)(src + 4);
        u16x8 p;
        p[0] = f2bf(a.x); p[1] = f2bf(a.y); p[2] = f2bf(a.z); p[3] = f2bf(a.w);
        p[4] = f2bf(c.x); p[5] = f2bf(c.y); p[6] = f2bf(c.z); p[7] = f2bf(c.w);
        *(u16x8*)(dst) = p;
    } else if (bid < 4352) {
        // ---- W1 fold role ----
        float* part = sh;          // [256]
        float* s1ld = sh + 256;    // [128]
        float* wred = sh + 384;    // [4]
        int bo = bid - 4096;
        int b = bo >> 7, o = bo & 127;
        // step 1: styles1[b][*] (each pair of threads: one 512-dot, split in half)
        {
            int i = tid >> 1, half = tid & 1;
            const float* x = wsv + (b * 2 + 0) * 512 + half * 256;
            const float* W = a1W + i * 512 + half * 256;
            float s = 0.f;
            for (int j = 0; j < 256; j += 4) {
                float4 xv = *(const float4*)(x + j);
                float4 wv = *(const float4*)(W + j);
                s += xv.x * wv.x + xv.y * wv.y + xv.z * wv.z + xv.w * wv.w;
            }
            part[tid] = s;
        }
        __syncthreads();
        if (tid < 128) s1ld[tid] = (part[2 * tid] + part[2 * tid + 1]) * G512 + a1b[tid];
        __syncthreads();
        // step 2: demod sum over 1152 modulated weights
        float ds = 0.f;
        for (int e = tid; e < 1152; e += 256) {
            int i = e / 9;
            float w = w1g[o * 1152 + e] * s1ld[i];
            ds += w * w;
        }
#pragma unroll
        for (int d = 1; d < 64; d <<= 1) ds += __shfl_xor(ds, d);
        if ((tid & 63) == 0) wred[tid >> 6] = ds;
        __syncthreads();
        float dm = rsqrtf(wred[0] + wred[1] + wred[2] + wred[3] + 1e-8f);
        // step 3: write folded bf16 [b][k][o][i]
        u16* w1out = (u16*)(wsb_nr + WS_W1);
#pragma unroll 3
        for (int p = tid; p < 576; p += 256) {
            int k = p >> 6, i0 = (p & 63) * 2;
            float v0 = w1g[(o * 128 + i0) * 9 + k] * s1ld[i0] * dm;
            float v1 = w1g[(o * 128 + i0 + 1) * 9 + k] * s1ld[i0 + 1] * dm;
            unsigned pack = (unsigned)f2bf(v0) | ((unsigned)f2bf(v1) << 16);
            *(unsigned*)&w1out[(size_t)(((b * 9 + k) * 128 + o) * 128) + i0] = pack;
        }
    } else {
        // ---- zeropage + styles2 + W2 fold role ----
        float* s2ld = sh;  // [256]
        float* wsf = (float*)wsb_nr;
        int b2 = tid >> 7, i = tid & 127;
        float s = dot512(wsv + (b2 * 2 + 1) * 512, a2W + i * 512);
        s2ld[tid] = (s * G512 + a2b[i]) * G128;
        if (tid < 64) wsf[tid] = 0.f;  // zeropage
        __syncthreads();
#pragma unroll
        for (int r = 0; r < 3; ++r) {
            int id = tid + r * 256;  // < 768
            int b3 = id / 384;
            int rem = id - b3 * 384;
            int o2 = rem >> 7;
            int ii = rem & 127;
            wsf[WS_W2F / 4 + id] = w2[o2 * 128 + ii] * s2ld[b3 * 128 + ii];
        }
    }
}

// ---------------- kernel 1: gathered GEMM conv1 + fused epilogue (R4 structure) ----------------
__global__ __launch_bounds__(256, 2) void k1_conv(
    const int* __restrict__ neigh, const int* __restrict__ ispad,
    const float* __restrict__ noise_c, const float* __restrict__ nstr,
    const float* __restrict__ bias1, const unsigned char* __restrict__ wsb,
    float* __restrict__ out)
{
    __shared__ u16 As[128 * 128];  // 32KB, 128 faces x 128ch, 16B-chunk XOR swizzled
    __shared__ u16 Bs[128 * 128];  // 32KB, 128 o x 128 k, 16B-chunk XOR swizzled

    int tid = threadIdx.x;
    int wv = tid >> 6, lane = tid & 63;
    int quad = lane >> 4, l15 = lane & 15;
    int f0 = blockIdx.x * 128;
    int b = f0 >> 16;
    const u16* cst = (const u16*)(wsb + WS_CONST);
    const u16* w1ws = (const u16*)(wsb + WS_W1) + (size_t)b * 147456;  // 9*128*128
    const char* zp = (const char*)wsb;

    int nidx[8];   // neigh row base (A)
    int cg16[8];   // swizzled within-row chunk byte offset (A and B share formula)
    int brow[8];   // B row byte base
    int ldso[8];   // wave-uniform LDS byte base per issue
#pragma unroll
    for (int r = 0; r < 8; ++r) {
        int cid = ((wv * 8 + r) << 6) + lane;
        int row = cid >> 4;
        int slot = cid & 15;
        nidx[r] = (f0 + row) * 9;
        cg16[r] = ((slot ^ (row & 15)) << 4);
        brow[r] = row << 8;  // row * 256 bytes
        ldso[r] = (wv * 8 + r) << 10;
    }

    f32x4 acc[4][4] = {};
    int wm = wv & 1, wn = wv >> 1;

    for (int k = 0; k < 9; ++k) {
        __syncthreads();
        // stage A (gather, masked -> zeropage), swizzled write
#pragma unroll
        for (int r = 0; r < 8; ++r) {
            int idx = neigh[nidx[r] + k];
            bool valid = (ispad[nidx[r] + k] == 0) && ((unsigned)idx < 131072u);
            const char* src = valid ? ((const char*)(cst + ((size_t)(idx & 65535) << 7))) : zp;
            gl_lds16(src + cg16[r], (char*)As + ldso[r]);
        }
        // stage B (from pre-folded ws), same swizzled write
        const char* bsrc = (const char*)(w1ws + k * 16384);
#pragma unroll
        for (int r = 0; r < 8; ++r) {
            gl_lds16(bsrc + brow[r] + cg16[r], (char*)Bs + ldso[r]);
        }
        __syncthreads();
#pragma unroll
        for (int s = 0; s < 4; ++s) {
            bf16x8 af[4], bfr[4];
#pragma unroll
            for (int mt = 0; mt < 4; ++mt) {
                int face = wm * 64 + mt * 16 + l15;
                int chunk = (s * 4 + quad) ^ (face & 15);
                af[mt] = *reinterpret_cast<const bf16x8*>(&As[face * 128 + chunk * 8]);
            }
#pragma unroll
            for (int nt = 0; nt < 4; ++nt) {
                int o = wn * 64 + nt * 16 + l15;
                int chunk = (s * 4 + quad) ^ (o & 15);
                bfr[nt] = *reinterpret_cast<const bf16x8*>(&Bs[o * 128 + chunk * 8]);
            }
#pragma unroll
            for (int mt = 0; mt < 4; ++mt)
#pragma unroll
                for (int nt = 0; nt < 4; ++nt)
                    acc[mt][nt] = __builtin_amdgcn_mfma_f32_16x16x32_bf16(
                        af[mt], bfr[nt], acc[mt][nt], 0, 0, 0);
        }
    }

    // epilogue: + noise + bias1, lrelu(0.2)*sqrt(2), clip +-256, fp32 store
    float ns = nstr[0];
    float b1v[4];
#pragma unroll
    for (int nt = 0; nt < 4; ++nt) b1v[nt] = bias1[wn * 64 + nt * 16 + l15];
#pragma unroll
    for (int mt = 0; mt < 4; ++mt) {
#pragma unroll
        for (int r = 0; r < 4; ++r) {
            int face = f0 + wm * 64 + mt * 16 + quad * 4 + r;
            float nz = noise_c[face & 65535] * ns;
#pragma unroll
            for (int nt = 0; nt < 4; ++nt) {
                float v = acc[mt][nt][r] + nz + b1v[nt];
                v = (v > 0.f) ? v : 0.2f * v;
                v *= 1.41421356f;
                v = fminf(fmaxf(v, -256.f), 256.f);
                out[(size_t)face * 128 + wn * 64 + nt * 16 + l15] = v;
            }
        }
    }
}

// ---------------- kernel 2: conv2 (k=1 gather) + bias + clip ----------------
__global__ __launch_bounds__(256) void k2_img(
    const int* __restrict__ neigh, const int* __restrict__ ispad,
    const float* __restrict__ w2f, const float* __restrict__ bias2,
    const float* __restrict__ xbuf, float* __restrict__ imgout)
{
    __shared__ float ws2[768];
    int tid = threadIdx.x;
    ws2[tid] = w2f[tid];
    ws2[tid + 256] = w2f[tid + 256];
    ws2[tid + 512] = w2f[tid + 512];
    __syncthreads();
    int wv = tid >> 6, lane = tid & 63;
    int g = lane >> 4, sub = lane & 15;
    int face = blockIdx.x * 16 + wv * 4 + g;
    int b = face >> 16;
    int idx = neigh[face * 9];
    bool valid = (ispad[face * 9] == 0) && ((unsigned)idx < 131072u);
    float a0 = 0.f, a1 = 0.f, a2 = 0.f;
    if (valid) {
        float4 d0 = *(const float4*)(xbuf + (size_t)idx * 128 + sub * 8);
        float4 d1 = *(const float4*)(xbuf + (size_t)idx * 128 + sub * 8 + 4);
        float f[8] = {d0.x, d0.y, d0.z, d0.w, d1.x, d1.y, d1.z, d1.w};
        const float* w0 = &ws2[(b * 3 + 0) * 128 + sub * 8];
        const float* w1 = &ws2[(b * 3 + 1) * 128 + sub * 8];
        const float* w2p = &ws2[(b * 3 + 2) * 128 + sub * 8];
#pragma unroll
        for (int j = 0; j < 8; ++j) {
            a0 += f[j] * w0[j];
            a1 += f[j] * w1[j];
            a2 += f[j] * w2p[j];
        }
    }
#pragma unroll
    for (int d = 1; d < 16; d <<= 1) {
        a0 += __shfl_xor(a0, d);
        a1 += __shfl_xor(a1, d);
        a2 += __shfl_xor(a2, d);
    }
    if (sub < 3) {
        float v = (sub == 0) ? a0 : (sub == 1) ? a1 : a2;
        v += bias2[sub];
        v = fminf(fmaxf(v, -256.f), 256.f);
        imgout[face * 3 + sub] = v;
    }
}

extern "C" void kernel_launch(void* const* d_in, const int* in_sizes, int n_in,
                              void* d_out, int out_size, void* d_ws, size_t ws_size,
                              hipStream_t stream) {
    const int* neigh = (const int*)d_in[0];
    const int* ispad = (const int*)d_in[1];
    const float* wsv = (const float*)d_in[2];
    const float* cst = (const float*)d_in[3];
    const float* a1W = (const float*)d_in[4];
    const float* a1b = (const float*)d_in[5];
    const float* w1g = (const float*)d_in[6];
    const float* noise_c = (const float*)d_in[7];
    const float* nstr = (const float*)d_in[8];
    const float* bias1 = (const float*)d_in[9];
    const float* a2W = (const float*)d_in[10];
    const float* a2b = (const float*)d_in[11];
    const float* w2 = (const float*)d_in[12];
    const float* bias2 = (const float*)d_in[13];
    float* out = (float*)d_out;
    unsigned char* wsb = (unsigned char*)d_ws;

    k0_all<<<4353, 256, 0, stream>>>(cst, wsv, a1W, a1b, a2W, a2b, w1g, w2, wsb);
    k1_conv<<<1024, 256, 0, stream>>>(neigh, ispad, noise_c, nstr, bias1, wsb, out);
    k2_img<<<8192, 256, 0, stream>>>(neigh, ispad, (const float*)(wsb + WS_W2F), bias2,
                                     out, out + XELEMS);
}